// Round 2
// baseline (317.858 us; speedup 1.0000x reference)
//
#include <hip/hip_runtime.h>
#include <hip/hip_bf16.h>

#define BS   8192
#define TT   8
#define NB   128
#define BLK  64
#define EPS  1e-7f

typedef __attribute__((ext_vector_type(4))) float f32x4;

// Vectorized zero fill: 256 MiB of zeros, float4 nontemporal stores.
// 8192 blocks x 256 threads, grid-stride: 16,777,216 float4 stores, 8/thread.
// Replaces rocclr fillBufferAligned (observed ~162 us for this buffer).
__global__ __launch_bounds__(256) void zero_fill(f32x4* __restrict__ out)
{
    const size_t n4     = (size_t)BS * BS / 4;   // 16,777,216
    const size_t stride = (size_t)gridDim.x * blockDim.x;
    size_t i = (size_t)blockIdx.x * blockDim.x + threadIdx.x;
    const f32x4 z = {0.f, 0.f, 0.f, 0.f};
    for (; i < n4; i += stride) {
        __builtin_nontemporal_store(z, &out[i]);
    }
}

// One block per sub-batch (128 blocks, 256 threads).
// Thread mapping: row = tid>>2 (0..63), part = tid&3 (0..3) -> 16-wide feature chunks.
__global__ __launch_bounds__(256) void attn_blocks(
    const float* __restrict__ x,
    const float* __restrict__ W1, const float* __restrict__ b1,
    const float* __restrict__ W2, const float* __restrict__ b2,
    const float* __restrict__ W3, const float* __restrict__ b3,
    const int*   __restrict__ sub_batches,
    float* __restrict__ out)
{
    __shared__ float sW1[2 * 32];
    __shared__ float sb1[32];
    __shared__ float sW2[32 * 64];
    __shared__ float sb2[64];
    __shared__ float sW3[64 * 64];
    __shared__ float sb3[64];
    __shared__ float h1[64][33];    // +1 pad: avoid 32-bank aliasing
    __shared__ float h2[64][65];
    __shared__ float h3[64][65];
    __shared__ float attn[64][65];
    __shared__ float mcol[64];
    __shared__ float rsum[64][4];

    const int tid = threadIdx.x;
    const int n   = blockIdx.x;
    const int start = sub_batches[2 * n];   // sub_batches[n][0]

    // ---- stage weights into LDS ----
    for (int i = tid; i < 2 * 32; i += 256)  sW1[i] = W1[i];
    if (tid < 32)                            sb1[tid] = b1[tid];
    for (int i = tid; i < 32 * 64; i += 256) sW2[i] = W2[i];
    if (tid < 64)                            sb2[tid] = b2[tid];
    for (int i = tid; i < 64 * 64; i += 256) sW3[i] = W3[i];
    if (tid >= 64 && tid < 128)              sb3[tid - 64] = b3[tid - 64];
    __syncthreads();

    const int row  = tid >> 2;   // 0..63
    const int part = tid & 3;    // 0..3

    // xt = x[:, -1]  -> x[r, T-1, c]
    const int r  = start + row;
    const float x0 = x[((long long)r * TT + (TT - 1)) * 2 + 0];
    const float x1 = x[((long long)r * TT + (TT - 1)) * 2 + 1];

    // ---- layer 1: h1 = relu(xt @ W1 + b1), 32 feats, 8 per thread ----
    for (int f = part * 8; f < part * 8 + 8; ++f) {
        float v = fmaf(x0, sW1[f], fmaf(x1, sW1[32 + f], sb1[f]));
        h1[row][f] = v > 0.f ? v : 0.f;
    }
    __syncthreads();

    // ---- layer 2: h2 = relu(h1 @ W2 + b2), 64 feats, 16 per thread ----
    for (int f = part * 16; f < part * 16 + 16; ++f) {
        float acc = sb2[f];
        #pragma unroll
        for (int k = 0; k < 32; ++k) acc = fmaf(h1[row][k], sW2[k * 64 + f], acc);
        h2[row][f] = acc > 0.f ? acc : 0.f;
    }
    __syncthreads();

    // ---- layer 3: h3 = h2 @ W3 + b3 ----
    for (int f = part * 16; f < part * 16 + 16; ++f) {
        float acc = sb3[f];
        #pragma unroll
        for (int k = 0; k < 64; ++k) acc = fmaf(h2[row][k], sW3[k * 64 + f], acc);
        h3[row][f] = acc;
    }
    __syncthreads();

    // ---- gram: attn[i][j] = dot(h3[i], h3[j]) ----
    for (int j = part * 16; j < part * 16 + 16; ++j) {
        float acc = 0.f;
        #pragma unroll
        for (int k = 0; k < 64; ++k) acc = fmaf(h3[row][k], h3[j][k], acc);
        attn[row][j] = acc;
    }
    __syncthreads();

    // ---- reference softmax semantics:
    // m[j] = max_k attn[j][k]  (axis=2 max of row j; subtracted from COLUMN j)
    if (tid < 64) {
        float mx = attn[tid][0];
        #pragma unroll
        for (int k = 1; k < 64; ++k) mx = fmaxf(mx, attn[tid][k]);
        mcol[tid] = mx;
    }
    __syncthreads();

    // e[i][j] = exp(attn[i][j] - m[j]); row sums
    float ps = 0.f;
    for (int j = part * 16; j < part * 16 + 16; ++j) {
        float e = expf(attn[row][j] - mcol[j]);
        attn[row][j] = e;
        ps += e;
    }
    rsum[row][part] = ps;
    __syncthreads();

    const float s   = rsum[row][0] + rsum[row][1] + rsum[row][2] + rsum[row][3] + EPS;
    const float inv = 1.f / s;

    // ---- write 64x64 block at (start, start) ----
    const long long base = (long long)(start + row) * BS + start;
    for (int j = part * 16; j < part * 16 + 16; ++j) {
        out[base + j] = attn[row][j] * inv;
    }
}

extern "C" void kernel_launch(void* const* d_in, const int* in_sizes, int n_in,
                              void* d_out, int out_size, void* d_ws, size_t ws_size,
                              hipStream_t stream) {
    const float* x   = (const float*)d_in[0];
    const float* W1  = (const float*)d_in[1];
    const float* b1  = (const float*)d_in[2];
    const float* W2  = (const float*)d_in[3];
    const float* b2  = (const float*)d_in[4];
    const float* W3  = (const float*)d_in[5];
    const float* b3  = (const float*)d_in[6];
    const int*   sb  = (const int*)d_in[7];
    float* out = (float*)d_out;

    // Output is 8192x8192 fp32, block-diagonal. Harness poisons d_out with
    // 0xAA before every timed call, so all 256 MiB must be rewritten each
    // launch. Custom vectorized fill (named kernel -> visible in rocprof)
    // instead of rocclr fillBufferAligned, then overwrite the 128 diagonal
    // 64x64 blocks.
    zero_fill<<<8192, 256, 0, stream>>>((f32x4*)out);

    attn_blocks<<<NB, 256, 0, stream>>>(x, W1, b1, W2, b2, W3, b3, sb, out);
}

// Round 3
// 295.033 us; speedup vs baseline: 1.0774x; 1.0774x over previous
//
#include <hip/hip_runtime.h>
#include <hip/hip_bf16.h>

#define BS   8192
#define TT   8
#define NB   128
#define BLK  64
#define EPS  1e-7f

// One block per sub-batch (128 blocks, 256 threads).
// Thread mapping: row = tid>>2 (0..63), part = tid&3 (0..3) -> 16-wide feature chunks.
__global__ __launch_bounds__(256) void attn_blocks(
    const float* __restrict__ x,
    const float* __restrict__ W1, const float* __restrict__ b1,
    const float* __restrict__ W2, const float* __restrict__ b2,
    const float* __restrict__ W3, const float* __restrict__ b3,
    const int*   __restrict__ sub_batches,
    float* __restrict__ out)
{
    __shared__ float sW1[2 * 32];
    __shared__ float sb1[32];
    __shared__ float sW2[32 * 64];
    __shared__ float sb2[64];
    __shared__ float sW3[64 * 64];
    __shared__ float sb3[64];
    __shared__ float h1[64][33];    // +1 pad: avoid 32-bank aliasing
    __shared__ float h2[64][65];
    __shared__ float h3[64][65];
    __shared__ float attn[64][65];
    __shared__ float mcol[64];
    __shared__ float rsum[64][4];

    const int tid = threadIdx.x;
    const int n   = blockIdx.x;
    const int start = sub_batches[2 * n];   // sub_batches[n][0]

    // ---- stage weights into LDS ----
    for (int i = tid; i < 2 * 32; i += 256)  sW1[i] = W1[i];
    if (tid < 32)                            sb1[tid] = b1[tid];
    for (int i = tid; i < 32 * 64; i += 256) sW2[i] = W2[i];
    if (tid < 64)                            sb2[tid] = b2[tid];
    for (int i = tid; i < 64 * 64; i += 256) sW3[i] = W3[i];
    if (tid >= 64 && tid < 128)              sb3[tid - 64] = b3[tid - 64];
    __syncthreads();

    const int row  = tid >> 2;   // 0..63
    const int part = tid & 3;    // 0..3

    // xt = x[:, -1]  -> x[r, T-1, c]
    const int r  = start + row;
    const float x0 = x[((long long)r * TT + (TT - 1)) * 2 + 0];
    const float x1 = x[((long long)r * TT + (TT - 1)) * 2 + 1];

    // ---- layer 1: h1 = relu(xt @ W1 + b1), 32 feats, 8 per thread ----
    for (int f = part * 8; f < part * 8 + 8; ++f) {
        float v = fmaf(x0, sW1[f], fmaf(x1, sW1[32 + f], sb1[f]));
        h1[row][f] = v > 0.f ? v : 0.f;
    }
    __syncthreads();

    // ---- layer 2: h2 = relu(h1 @ W2 + b2), 64 feats, 16 per thread ----
    for (int f = part * 16; f < part * 16 + 16; ++f) {
        float acc = sb2[f];
        #pragma unroll
        for (int k = 0; k < 32; ++k) acc = fmaf(h1[row][k], sW2[k * 64 + f], acc);
        h2[row][f] = acc > 0.f ? acc : 0.f;
    }
    __syncthreads();

    // ---- layer 3: h3 = h2 @ W3 + b3 ----
    for (int f = part * 16; f < part * 16 + 16; ++f) {
        float acc = sb3[f];
        #pragma unroll
        for (int k = 0; k < 64; ++k) acc = fmaf(h2[row][k], sW3[k * 64 + f], acc);
        h3[row][f] = acc;
    }
    __syncthreads();

    // ---- gram: attn[i][j] = dot(h3[i], h3[j]) ----
    for (int j = part * 16; j < part * 16 + 16; ++j) {
        float acc = 0.f;
        #pragma unroll
        for (int k = 0; k < 64; ++k) acc = fmaf(h3[row][k], h3[j][k], acc);
        attn[row][j] = acc;
    }
    __syncthreads();

    // ---- reference softmax semantics:
    // m[j] = max_k attn[j][k]  (axis=2 max of row j; subtracted from COLUMN j)
    if (tid < 64) {
        float mx = attn[tid][0];
        #pragma unroll
        for (int k = 1; k < 64; ++k) mx = fmaxf(mx, attn[tid][k]);
        mcol[tid] = mx;
    }
    __syncthreads();

    // e[i][j] = exp(attn[i][j] - m[j]); row sums
    float ps = 0.f;
    for (int j = part * 16; j < part * 16 + 16; ++j) {
        float e = expf(attn[row][j] - mcol[j]);
        attn[row][j] = e;
        ps += e;
    }
    rsum[row][part] = ps;
    __syncthreads();

    const float s   = rsum[row][0] + rsum[row][1] + rsum[row][2] + rsum[row][3] + EPS;
    const float inv = 1.f / s;

    // ---- write 64x64 block at (start, start) ----
    const long long base = (long long)(start + row) * BS + start;
    for (int j = part * 16; j < part * 16 + 16; ++j) {
        out[base + j] = attn[row][j] * inv;
    }
}

extern "C" void kernel_launch(void* const* d_in, const int* in_sizes, int n_in,
                              void* d_out, int out_size, void* d_ws, size_t ws_size,
                              hipStream_t stream) {
    const float* x   = (const float*)d_in[0];
    const float* W1  = (const float*)d_in[1];
    const float* b1  = (const float*)d_in[2];
    const float* W2  = (const float*)d_in[3];
    const float* b2  = (const float*)d_in[4];
    const float* W3  = (const float*)d_in[5];
    const float* b3  = (const float*)d_in[6];
    const int*   sb  = (const int*)d_in[7];
    float* out = (float*)d_out;

    // Output is 8192x8192 fp32, block-diagonal. Harness poisons d_out with
    // 0xAA before every timed call, so all 256 MiB must be rewritten each
    // launch. rocclr's fillBufferAligned (via hipMemsetAsync) sustains
    // ~6.4 TB/s -- measured faster than a custom float4 nontemporal fill
    // kernel (round 2: +22 us regression). Keep the memset.
    hipMemsetAsync(out, 0, (size_t)BS * BS * sizeof(float), stream);

    attn_blocks<<<NB, 256, 0, stream>>>(x, W1, b1, W2, b2, W3, b3, sb, out);
}